// Round 6
// baseline (226.945 us; speedup 1.0000x reference)
//
#include <hip/hip_runtime.h>
#include <hip/hip_bf16.h>

// B=256, C_IN=6, L=512, C1=32, C2=D=64, NCLASS=10.
// ws: qo bf16 @0, ko bf16 @16M, vt bf16 [b][d][key] @32M, partial f32 @48M.
// qo is pre-scaled by 1/sqrt(64) (exact exponent shift) so attn skips the mul.

#define NB 256
#define LL 512
#define CIN 6
#define C1 32
#define C2 64
#define NCLASS 10

typedef __bf16 bf16x8 __attribute__((ext_vector_type(8)));
typedef float f32x4 __attribute__((ext_vector_type(4)));
typedef unsigned short us4 __attribute__((ext_vector_type(4)));

static __device__ __forceinline__ unsigned short f2b(float f) {
    __bf16 h = (__bf16)f;                       // RNE f32->bf16
    return __builtin_bit_cast(unsigned short, h);
}

// ---------------------------------------------------------------------------
// Kernel A (fused): conv1(VALU) -> conv2(MFMA) -> bn2+relu -> q/k/v MFMA.
// Block = (b, 64 L-rows): grid 2048 -> 8 blocks/CU of grid parallelism.
// Peak LDS 20 KB. Hs/Cs/Vs writes are wave-private -> fewer barriers (8).
// ---------------------------------------------------------------------------
__global__ __launch_bounds__(256) void conv_qkv(
    const float* __restrict__ x,
    const float* __restrict__ w1, const float* __restrict__ cb1,
    const float* __restrict__ g1, const float* __restrict__ be1,
    const float* __restrict__ m1, const float* __restrict__ v1,
    const float* __restrict__ w2, const float* __restrict__ cb2,
    const float* __restrict__ g2, const float* __restrict__ be2,
    const float* __restrict__ m2, const float* __restrict__ v2,
    const float* __restrict__ wq, const float* __restrict__ bq,
    const float* __restrict__ wk, const float* __restrict__ bk,
    const float* __restrict__ wv, const float* __restrict__ bvp,
    unsigned short* __restrict__ qo, unsigned short* __restrict__ ko,
    unsigned short* __restrict__ vt)
{
    const int b  = blockIdx.x;
    const int l0 = blockIdx.y * 64;
    const int t  = threadIdx.x;
    const int w = t >> 6, lane = t & 63, quad = lane >> 4, lc = lane & 15;
    const int rowbase = b * LL + l0;

    // aliased phases:
    //  A: xs[6][68] f32 @0 | h1b[66][40] @1632 | W2s[64][104] @6912  (20224 B)
    //  B: Hs[64][72] @0   C: Cs[64][72] @0   D: Vs[64][72] @0
    __shared__ __align__(16) char smem[20224];
    float*          xs  = (float*)smem;
    unsigned short* h1b = (unsigned short*)(smem + 1632);
    unsigned short* W2s = (unsigned short*)(smem + 6912);
    unsigned short* Hs  = (unsigned short*)smem;
    unsigned short* Cs  = (unsigned short*)smem;
    unsigned short* Vs  = (unsigned short*)smem;

    // ---- stage W2 (k' = dl*32+ci packing; conflict-light writes) + x -----
    for (int idx = t; idx < 2048; idx += 256) {
        int c2 = idx >> 5, ci = idx & 31;
        const float* wp = w2 + c2 * 96 + ci * 3;
        W2s[c2 * 104 +       ci] = f2b(wp[0]);
        W2s[c2 * 104 + 32 +  ci] = f2b(wp[1]);
        W2s[c2 * 104 + 64 +  ci] = f2b(wp[2]);
    }
    for (int idx = t; idx < CIN * 68; idx += 256) {
        int c = idx / 68, j = idx % 68;
        int l = l0 - 2 + j;
        xs[c * 68 + j] = (l >= 0 && l < LL) ? x[((size_t)b * CIN + c) * LL + l] : 0.f;
    }
    __syncthreads();

    // ---- conv1 + bn1 + relu -> h1b[j][ci], j=0..65 <-> pos l0-1+j --------
    for (int idx = t; idx < 66 * C1; idx += 256) {
        int j = idx >> 5, c = idx & 31;
        int p = l0 - 1 + j;
        float y = 0.f;
        if (p >= 0 && p < LL) {
            float inv = g1[c] * rsqrtf(v1[c] + 1e-5f);
            float sh  = be1[c] + (cb1[c] - m1[c]) * inv;
            float acc = 0.f;
            #pragma unroll
            for (int ci = 0; ci < CIN; ci++) {
                const float* wp = w1 + (c * CIN + ci) * 3;
                acc += xs[ci * 68 + j] * wp[0] + xs[ci * 68 + j + 1] * wp[1]
                     + xs[ci * 68 + j + 2] * wp[2];
            }
            y = acc * inv + sh;
            y = y > 0.f ? y : 0.f;
        }
        h1b[j * 40 + c] = f2b(y);
    }
    __syncthreads();

    // ---- conv2: C' = W2 · X^T  (M=64 c2, N=64 rows, K=96); wave = 16 rows -
    bf16x8 bX[3], aW2[4][3];
    #pragma unroll
    for (int kc = 0; kc < 3; kc++)
        bX[kc] = *(const bf16x8*)&h1b[(w * 16 + lc + kc) * 40 + quad * 8];
    #pragma unroll
    for (int nt = 0; nt < 4; nt++)
        #pragma unroll
        for (int kc = 0; kc < 3; kc++)
            aW2[nt][kc] = *(const bf16x8*)&W2s[(nt * 16 + lc) * 104 + kc * 32 + quad * 8];

    f32x4 acc2[4];
    #pragma unroll
    for (int nt = 0; nt < 4; nt++) {
        f32x4 a = {0.f, 0.f, 0.f, 0.f};
        a = __builtin_amdgcn_mfma_f32_16x16x32_bf16(aW2[nt][0], bX[0], a, 0, 0, 0);
        a = __builtin_amdgcn_mfma_f32_16x16x32_bf16(aW2[nt][1], bX[1], a, 0, 0, 0);
        acc2[nt] = __builtin_amdgcn_mfma_f32_16x16x32_bf16(aW2[nt][2], bX[2], a, 0, 0, 0);
    }
    __syncthreads();                       // region A dead

    // ---- bn2 + relu -> Hs[row][c2]; wave-private rows (no barrier needed) -
    #pragma unroll
    for (int nt = 0; nt < 4; nt++) {
        const float4 gv  = *(const float4*)&g2[nt * 16 + quad * 4];
        const float4 vv  = *(const float4*)&v2[nt * 16 + quad * 4];
        const float4 bev = *(const float4*)&be2[nt * 16 + quad * 4];
        const float4 cbv = *(const float4*)&cb2[nt * 16 + quad * 4];
        const float4 mv  = *(const float4*)&m2[nt * 16 + quad * 4];
        float inv[4], sh[4];
        inv[0] = gv.x * rsqrtf(vv.x + 1e-5f); sh[0] = bev.x + (cbv.x - mv.x) * inv[0];
        inv[1] = gv.y * rsqrtf(vv.y + 1e-5f); sh[1] = bev.y + (cbv.y - mv.y) * inv[1];
        inv[2] = gv.z * rsqrtf(vv.z + 1e-5f); sh[2] = bev.z + (cbv.z - mv.z) * inv[2];
        inv[3] = gv.w * rsqrtf(vv.w + 1e-5f); sh[3] = bev.w + (cbv.w - mv.w) * inv[3];
        us4 pk;
        #pragma unroll
        for (int r = 0; r < 4; r++) {
            float y = acc2[nt][r] * inv[r] + sh[r];
            y = y > 0.f ? y : 0.f;
            pk[r] = f2b(y);
        }
        *(us4*)&Hs[(w * 16 + lc) * 72 + nt * 16 + quad * 4] = pk;
    }
    // own-wave rows: DS pipe is in-order, read back immediately
    bf16x8 aH[2];
    #pragma unroll
    for (int kc = 0; kc < 2; kc++)
        aH[kc] = *(const bf16x8*)&Hs[(w * 16 + lc) * 72 + kc * 32 + quad * 8];

    // ---- q, k: C' = W · H^T; q pre-scaled by 0.125 ------------------------
    for (int p = 0; p < 2; p++) {
        const float* wsrc = p ? wk : wq;
        const float* bsrc = p ? bk : bq;
        unsigned short* osrc = p ? ko : qo;
        const float scl = p ? 1.0f : 0.125f;
        #pragma unroll
        for (int nt = 0; nt < 4; nt++) {
            bf16x8 aW[2];
            #pragma unroll
            for (int kc = 0; kc < 2; kc++) {
                const float* wp = wsrc + (size_t)(nt * 16 + lc) * 64 + kc * 32 + quad * 8;
                float4 f0 = *(const float4*)wp;
                float4 f1 = *(const float4*)(wp + 4);
                bf16x8 tmp;
                tmp[0] = (__bf16)f0.x; tmp[1] = (__bf16)f0.y;
                tmp[2] = (__bf16)f0.z; tmp[3] = (__bf16)f0.w;
                tmp[4] = (__bf16)f1.x; tmp[5] = (__bf16)f1.y;
                tmp[6] = (__bf16)f1.z; tmp[7] = (__bf16)f1.w;
                aW[kc] = tmp;
            }
            const float4 bb = *(const float4*)&bsrc[nt * 16 + quad * 4];
            f32x4 a = {0.f, 0.f, 0.f, 0.f};
            a = __builtin_amdgcn_mfma_f32_16x16x32_bf16(aW[0], aH[0], a, 0, 0, 0);
            a = __builtin_amdgcn_mfma_f32_16x16x32_bf16(aW[1], aH[1], a, 0, 0, 0);
            us4 pk;
            pk[0] = f2b((a[0] + bb.x) * scl); pk[1] = f2b((a[1] + bb.y) * scl);
            pk[2] = f2b((a[2] + bb.z) * scl); pk[3] = f2b((a[3] + bb.w) * scl);
            *(us4*)&Cs[(w * 16 + lc) * 72 + nt * 16 + quad * 4] = pk;   // own rows
        }
        __syncthreads();
        // 64x64 shorts = 512 uint4 -> 2 iterations
        #pragma unroll
        for (int i = 0; i < 2; i++) {
            int idx = i * 256 + t;             // [0,512)
            int row = idx >> 3, dcol = (idx & 7) * 8;
            uint4 rd = *(const uint4*)&Cs[row * 72 + dcol];
            *(uint4*)(osrc + (size_t)(rowbase + row) * 64 + dcol) = rd;
        }
        __syncthreads();
    }

    // ---- v: H · Wv^T; regs along keys -> Vs[d][key] (wave-private cols) --
    #pragma unroll
    for (int nt = 0; nt < 4; nt++) {
        bf16x8 bW[2];
        #pragma unroll
        for (int kc = 0; kc < 2; kc++) {
            const float* wp = wv + (size_t)(nt * 16 + lc) * 64 + kc * 32 + quad * 8;
            float4 f0 = *(const float4*)wp;
            float4 f1 = *(const float4*)(wp + 4);
            bf16x8 tmp;
            tmp[0] = (__bf16)f0.x; tmp[1] = (__bf16)f0.y;
            tmp[2] = (__bf16)f0.z; tmp[3] = (__bf16)f0.w;
            tmp[4] = (__bf16)f1.x; tmp[5] = (__bf16)f1.y;
            tmp[6] = (__bf16)f1.z; tmp[7] = (__bf16)f1.w;
            bW[kc] = tmp;
        }
        const float bvv = bvp[nt * 16 + lc];
        f32x4 a = {0.f, 0.f, 0.f, 0.f};
        a = __builtin_amdgcn_mfma_f32_16x16x32_bf16(aH[0], bW[0], a, 0, 0, 0);
        a = __builtin_amdgcn_mfma_f32_16x16x32_bf16(aH[1], bW[1], a, 0, 0, 0);
        us4 pk;
        pk[0] = f2b(a[0] + bvv); pk[1] = f2b(a[1] + bvv);
        pk[2] = f2b(a[2] + bvv); pk[3] = f2b(a[3] + bvv);
        *(us4*)&Vs[(nt * 16 + lc) * 72 + w * 16 + quad * 4] = pk;
    }
    __syncthreads();
    // 64x64 shorts = 512 uint4 -> vt[b][d][l0..l0+63]
    #pragma unroll
    for (int i = 0; i < 2; i++) {
        int idx = i * 256 + t;                 // [0,512)
        int d = idx >> 3, ch = (idx & 7) * 8;
        uint4 rd = *(const uint4*)&Vs[d * 72 + ch];
        *(uint4*)(vt + ((size_t)b * 64 + d) * 512 + l0 + ch) = rd;
    }
}

// ---------------------------------------------------------------------------
// Kernel B: MFMA flash attention + pooling. Block = (b, 128-row q-tile),
// 4 waves x 32 rows. K/V staged per 64-key stage in MFMA-frag order, with
// REGISTER PREFETCH: stage s+1's global loads issue before the compute of
// stage s, hiding VMEM latency behind MFMA+exp. LDS 27.6 KB, 2 barriers/stage.
// ---------------------------------------------------------------------------
__global__ __launch_bounds__(256) void attn_mfma(
    const unsigned short* __restrict__ q, const unsigned short* __restrict__ k,
    const unsigned short* __restrict__ vt, float* __restrict__ partial)
{
    const int b = blockIdx.x, qt = blockIdx.y, t = threadIdx.x;
    const int w = t >> 6, lane = t & 63, quad = lane >> 4, lc = lane & 15;

    __shared__ unsigned short Kb[4096];        // 64 keys x 64 d, frag order
    __shared__ unsigned short Vb[4096];        // 64 d x 64 keys, frag order
    __shared__ unsigned short Ps[4][2][16][40];
    __shared__ float red[4][64];

    bf16x8 aQ[2][2];
    #pragma unroll
    for (int rt = 0; rt < 2; rt++) {
        const unsigned short* qrow =
            q + (size_t)(b * LL + qt * 128 + w * 32 + rt * 16 + lc) * 64;
        aQ[rt][0] = *(const bf16x8*)(qrow + quad * 8);
        aQ[rt][1] = *(const bf16x8*)(qrow + 32 + quad * 8);
    }

    f32x4 outacc[2][4];
    #pragma unroll
    for (int rt = 0; rt < 2; rt++)
        #pragma unroll
        for (int dt = 0; dt < 4; dt++) outacc[rt][dt] = (f32x4){0.f, 0.f, 0.f, 0.f};
    float den[2][4] = {{0.f, 0.f, 0.f, 0.f}, {0.f, 0.f, 0.f, 0.f}};

    const unsigned short* kbase = k + (size_t)b * LL * 64;
    const unsigned short* vbase = vt + (size_t)b * 64 * 512;

    // per-lane staging slots: u = w*2 + uu
    const int uK[2] = {w * 2, w * 2 + 1};
    // K slot u: cc=u>>2, nt=(u>>1)&1, kc=u&1 ; V slot u: cc=u>>2, dt=u&3
    uint4 kreg[2], vreg[2];
    #pragma unroll
    for (int uu = 0; uu < 2; uu++) {
        int u = uK[uu];
        kreg[uu] = *(const uint4*)(kbase +
            (size_t)((u >> 2) * 32 + ((u >> 1) & 1) * 16 + lc) * 64 + (u & 1) * 32 + quad * 8);
        vreg[uu] = *(const uint4*)(vbase +
            (size_t)((u & 3) * 16 + lc) * 512 + (u >> 2) * 32 + quad * 8);
    }

    for (int s = 0; s < 8; s++) {
        __syncthreads();                       // readers of stage s-1 done
        #pragma unroll
        for (int uu = 0; uu < 2; uu++) {
            int u = uK[uu];
            *(uint4*)&Kb[u * 512 + lane * 8] = kreg[uu];
            *(uint4*)&Vb[u * 512 + lane * 8] = vreg[uu];
        }
        if (s < 7) {                            // prefetch s+1 (in flight during compute)
            #pragma unroll
            for (int uu = 0; uu < 2; uu++) {
                int u = uK[uu];
                kreg[uu] = *(const uint4*)(kbase +
                    (size_t)((s + 1) * 64 + (u >> 2) * 32 + ((u >> 1) & 1) * 16 + lc) * 64
                    + (u & 1) * 32 + quad * 8);
                vreg[uu] = *(const uint4*)(vbase +
                    (size_t)((u & 3) * 16 + lc) * 512 + (s + 1) * 64 + (u >> 2) * 32 + quad * 8);
            }
        }
        __syncthreads();
        #pragma unroll
        for (int cc = 0; cc < 2; cc++) {       // 32 keys per chunk
            bf16x8 bK[2][2];
            #pragma unroll
            for (int nt = 0; nt < 2; nt++)
                #pragma unroll
                for (int kc = 0; kc < 2; kc++)
                    bK[nt][kc] = *(const bf16x8*)&Kb[(cc * 4 + nt * 2 + kc) * 512 + lane * 8];
            #pragma unroll
            for (int rt = 0; rt < 2; rt++)
                #pragma unroll
                for (int nt = 0; nt < 2; nt++) {
                    f32x4 sv = {0.f, 0.f, 0.f, 0.f};
                    sv = __builtin_amdgcn_mfma_f32_16x16x32_bf16(aQ[rt][0], bK[nt][0], sv, 0, 0, 0);
                    sv = __builtin_amdgcn_mfma_f32_16x16x32_bf16(aQ[rt][1], bK[nt][1], sv, 0, 0, 0);
                    #pragma unroll
                    for (int reg = 0; reg < 4; reg++) {
                        float p = __expf(sv[reg]);    // q pre-scaled by 1/8
                        den[rt][reg] += p;
                        Ps[w][rt][quad * 4 + reg][nt * 16 + lc] = f2b(p);
                    }
                }
            bf16x8 aP[2];                       // C->A via per-wave LDS (in-order)
            aP[0] = *(const bf16x8*)&Ps[w][0][lc][quad * 8];
            aP[1] = *(const bf16x8*)&Ps[w][1][lc][quad * 8];
            bf16x8 bV[4];
            #pragma unroll
            for (int dt = 0; dt < 4; dt++)
                bV[dt] = *(const bf16x8*)&Vb[(cc * 4 + dt) * 512 + lane * 8];
            #pragma unroll
            for (int rt = 0; rt < 2; rt++)
                #pragma unroll
                for (int dt = 0; dt < 4; dt++)
                    outacc[rt][dt] = __builtin_amdgcn_mfma_f32_16x16x32_bf16(
                        aP[rt], bV[dt], outacc[rt][dt], 0, 0, 0);
        }
    }

    // denominators: reduce over the quad's 16 lanes (key mod-16 classes)
    #pragma unroll
    for (int rt = 0; rt < 2; rt++)
        #pragma unroll
        for (int reg = 0; reg < 4; reg++) {
            float d2 = den[rt][reg];
            d2 += __shfl_xor(d2, 1);  d2 += __shfl_xor(d2, 2);
            d2 += __shfl_xor(d2, 4);  d2 += __shfl_xor(d2, 8);
            den[rt][reg] = d2;
        }
    // pooled partials over this wave's 32 rows
    #pragma unroll
    for (int dt = 0; dt < 4; dt++) {
        float ps = 0.f;
        #pragma unroll
        for (int rt = 0; rt < 2; rt++)
            #pragma unroll
            for (int reg = 0; reg < 4; reg++)
                ps += outacc[rt][dt][reg] / den[rt][reg];
        ps += __shfl_xor(ps, 16);
        ps += __shfl_xor(ps, 32);
        if (quad == 0) red[w][dt * 16 + lc] = ps;
    }
    __syncthreads();
    if (t < 64)
        partial[(size_t)(b * 4 + qt) * 64 + t] =
            red[0][t] + red[1][t] + red[2][t] + red[3][t];
}

// ---------------------------------------------------------------------------
// Kernel C: pooled = (sum of 4 partials)/512 ; logits = pooled @ fc_w^T + fc_b
// ---------------------------------------------------------------------------
__global__ __launch_bounds__(64) void fc_kernel(
    const float* __restrict__ partial,
    const float* __restrict__ fcw, const float* __restrict__ fcb,
    float* __restrict__ outp)
{
    const int b = blockIdx.x, t = threadIdx.x;
    __shared__ float pool[64];
    float s = 0.f;
    #pragma unroll
    for (int p = 0; p < 4; p++) s += partial[((size_t)b * 4 + p) * 64 + t];
    pool[t] = s * (1.0f / 512.0f);
    __syncthreads();
    if (t < NCLASS) {
        float acc = fcb[t];
        #pragma unroll
        for (int d = 0; d < 64; d++) acc += pool[d] * fcw[t * 64 + d];
        outp[b * NCLASS + t] = acc;
    }
}

// ---------------------------------------------------------------------------
extern "C" void kernel_launch(void* const* d_in, const int* in_sizes, int n_in,
                              void* d_out, int out_size, void* d_ws, size_t ws_size,
                              hipStream_t stream)
{
    const float* x   = (const float*)d_in[0];
    const float* w1  = (const float*)d_in[1];
    const float* cb1 = (const float*)d_in[2];
    const float* g1  = (const float*)d_in[3];
    const float* be1 = (const float*)d_in[4];
    const float* m1  = (const float*)d_in[5];
    const float* v1  = (const float*)d_in[6];
    const float* w2  = (const float*)d_in[7];
    const float* cb2 = (const float*)d_in[8];
    const float* g2  = (const float*)d_in[9];
    const float* be2 = (const float*)d_in[10];
    const float* m2  = (const float*)d_in[11];
    const float* v2  = (const float*)d_in[12];
    const float* wq  = (const float*)d_in[13];
    const float* bq  = (const float*)d_in[14];
    const float* wk  = (const float*)d_in[15];
    const float* bk  = (const float*)d_in[16];
    const float* wv  = (const float*)d_in[17];
    const float* bv  = (const float*)d_in[18];
    const float* fcw = (const float*)d_in[19];
    const float* fcb = (const float*)d_in[20];
    float* out = (float*)d_out;

    char* ws = (char*)d_ws;
    unsigned short* qo = (unsigned short*)(ws);                 // 16,777,216 B
    unsigned short* ko = (unsigned short*)(ws + 16777216u);
    unsigned short* vt = (unsigned short*)(ws + 33554432u);
    float* partial     = (float*)(ws + 50331648u);

    conv_qkv<<<dim3(NB, 8), 256, 0, stream>>>(x, w1, cb1, g1, be1, m1, v1,
                                              w2, cb2, g2, be2, m2, v2,
                                              wq, bq, wk, bk, wv, bv,
                                              qo, ko, vt);
    attn_mfma<<<dim3(NB, 4), 256, 0, stream>>>(qo, ko, vt, partial);
    fc_kernel<<<dim3(NB), 64, 0, stream>>>(partial, fcw, fcb, out);
}

// Round 7
// 173.772 us; speedup vs baseline: 1.3060x; 1.3060x over previous
//
#include <hip/hip_runtime.h>
#include <hip/hip_bf16.h>

// B=256, C_IN=6, L=512, C1=32, C2=D=64, NCLASS=10.
// ws: qo bf16 @0, ko @16M, vt [b][d][key] @32M, partial f32 @48M,
//     prepped bf16 weights @50.59M (w2p k'-packed, wqp(x0.125), wkp, wvp).

#define NB 256
#define LL 512
#define CIN 6
#define C1 32
#define C2 64
#define NCLASS 10

typedef __bf16 bf16x8 __attribute__((ext_vector_type(8)));
typedef float f32x4 __attribute__((ext_vector_type(4)));
typedef unsigned short us4 __attribute__((ext_vector_type(4)));

static __device__ __forceinline__ unsigned short f2b(float f) {
    __bf16 h = (__bf16)f;                       // RNE f32->bf16
    return __builtin_bit_cast(unsigned short, h);
}

// ---------------------------------------------------------------------------
// Kernel P: one-time weight conversion to bf16 (runs every launch; ~2 us).
// w2p[c2][k'=dl*32+ci]; wqp = wq * 0.125 (folds 1/sqrt(64), exact); wkp; wvp.
// ---------------------------------------------------------------------------
__global__ __launch_bounds__(256) void prep_weights(
    const float* __restrict__ w2, const float* __restrict__ wq,
    const float* __restrict__ wk, const float* __restrict__ wv,
    unsigned short* __restrict__ w2p, unsigned short* __restrict__ wqp,
    unsigned short* __restrict__ wkp, unsigned short* __restrict__ wvp)
{
    const int t = threadIdx.x;
    for (int idx = t; idx < 2048; idx += 256) {
        int c2 = idx >> 5, ci = idx & 31;
        const float* wp = w2 + c2 * 96 + ci * 3;
        w2p[c2 * 96 +      ci] = f2b(wp[0]);
        w2p[c2 * 96 + 32 + ci] = f2b(wp[1]);
        w2p[c2 * 96 + 64 + ci] = f2b(wp[2]);
    }
    for (int idx = t; idx < 4096; idx += 256) {
        wqp[idx] = f2b(wq[idx] * 0.125f);
        wkp[idx] = f2b(wk[idx]);
        wvp[idx] = f2b(wv[idx]);
    }
}

// ---------------------------------------------------------------------------
// Kernel A: conv1(VALU) -> conv2(MFMA) -> bn2+relu -> q/k/v MFMA.
// Block = (b, 128 L-rows), grid 1024. Weight frags read directly from global
// bf16 (L2-resident) -> zero per-block weight staging. Peak LDS 18.4 KB.
// ---------------------------------------------------------------------------
__global__ __launch_bounds__(256) void conv_qkv(
    const float* __restrict__ x,
    const float* __restrict__ w1, const float* __restrict__ cb1,
    const float* __restrict__ g1, const float* __restrict__ be1,
    const float* __restrict__ m1, const float* __restrict__ v1,
    const float* __restrict__ cb2,
    const float* __restrict__ g2, const float* __restrict__ be2,
    const float* __restrict__ m2, const float* __restrict__ v2,
    const float* __restrict__ bq, const float* __restrict__ bk,
    const float* __restrict__ bvp,
    const unsigned short* __restrict__ w2p, const unsigned short* __restrict__ wqp,
    const unsigned short* __restrict__ wkp, const unsigned short* __restrict__ wvp,
    unsigned short* __restrict__ qo, unsigned short* __restrict__ ko,
    unsigned short* __restrict__ vt)
{
    const int b  = blockIdx.x;
    const int l0 = blockIdx.y * 128;
    const int t  = threadIdx.x;
    const int w = t >> 6, lane = t & 63, quad = lane >> 4, lc = lane & 15;
    const int rowbase = b * LL + l0;

    // aliased phases:
    //  A: xs[6][132] f32 @0 (3168) | h1b[130][40] @3168 (10400)  = 13568 B
    //  B: Hs[128][72] @0 (18432)   C: Cs[128][72] @0   D: Vs[64][136] @0
    __shared__ __align__(16) char smem[18432];
    float*          xs  = (float*)smem;
    unsigned short* h1b = (unsigned short*)(smem + 3168);
    unsigned short* Hs  = (unsigned short*)smem;
    unsigned short* Cs  = (unsigned short*)smem;
    unsigned short* Vs  = (unsigned short*)smem;

    for (int idx = t; idx < CIN * 132; idx += 256) {
        int c = idx / 132, j = idx % 132;
        int l = l0 - 2 + j;
        xs[c * 132 + j] = (l >= 0 && l < LL) ? x[((size_t)b * CIN + c) * LL + l] : 0.f;
    }
    __syncthreads();

    // ---- conv1 + bn1 + relu -> h1b[j][ci], j=0..129 <-> pos l0-1+j -------
    for (int idx = t; idx < 130 * C1; idx += 256) {
        int j = idx >> 5, c = idx & 31;
        int p = l0 - 1 + j;
        float y = 0.f;
        if (p >= 0 && p < LL) {
            float inv = g1[c] * rsqrtf(v1[c] + 1e-5f);
            float sh  = be1[c] + (cb1[c] - m1[c]) * inv;
            float acc = 0.f;
            #pragma unroll
            for (int ci = 0; ci < CIN; ci++) {
                const float* wp = w1 + (c * CIN + ci) * 3;
                acc += xs[ci * 132 + j] * wp[0] + xs[ci * 132 + j + 1] * wp[1]
                     + xs[ci * 132 + j + 2] * wp[2];
            }
            y = acc * inv + sh;
            y = y > 0.f ? y : 0.f;
        }
        h1b[j * 40 + c] = f2b(y);
    }
    __syncthreads();

    // ---- conv2: C' = W2 · X^T  (M=64 c2, N=128 rows, K=96) ---------------
    bf16x8 bX[2][3], aW2[4][3];
    #pragma unroll
    for (int mt = 0; mt < 2; mt++)
        #pragma unroll
        for (int kc = 0; kc < 3; kc++)
            bX[mt][kc] = *(const bf16x8*)&h1b[(w * 32 + mt * 16 + lc + kc) * 40 + quad * 8];
    #pragma unroll
    for (int nt = 0; nt < 4; nt++)
        #pragma unroll
        for (int kc = 0; kc < 3; kc++)
            aW2[nt][kc] = *(const bf16x8*)(w2p + (nt * 16 + lc) * 96 + kc * 32 + quad * 8);

    f32x4 acc2[4][2];
    #pragma unroll
    for (int nt = 0; nt < 4; nt++)
        #pragma unroll
        for (int mt = 0; mt < 2; mt++) {
            f32x4 a = {0.f, 0.f, 0.f, 0.f};
            a = __builtin_amdgcn_mfma_f32_16x16x32_bf16(aW2[nt][0], bX[mt][0], a, 0, 0, 0);
            a = __builtin_amdgcn_mfma_f32_16x16x32_bf16(aW2[nt][1], bX[mt][1], a, 0, 0, 0);
            acc2[nt][mt] = __builtin_amdgcn_mfma_f32_16x16x32_bf16(aW2[nt][2], bX[mt][2], a, 0, 0, 0);
        }
    __syncthreads();                       // region A dead

    // ---- bn2 + relu -> Hs[row][c2] (wave-private rows) -------------------
    #pragma unroll
    for (int nt = 0; nt < 4; nt++) {
        const float4 gv  = *(const float4*)&g2[nt * 16 + quad * 4];
        const float4 vv  = *(const float4*)&v2[nt * 16 + quad * 4];
        const float4 bev = *(const float4*)&be2[nt * 16 + quad * 4];
        const float4 cbv = *(const float4*)&cb2[nt * 16 + quad * 4];
        const float4 mv  = *(const float4*)&m2[nt * 16 + quad * 4];
        float inv[4], sh[4];
        inv[0] = gv.x * rsqrtf(vv.x + 1e-5f); sh[0] = bev.x + (cbv.x - mv.x) * inv[0];
        inv[1] = gv.y * rsqrtf(vv.y + 1e-5f); sh[1] = bev.y + (cbv.y - mv.y) * inv[1];
        inv[2] = gv.z * rsqrtf(vv.z + 1e-5f); sh[2] = bev.z + (cbv.z - mv.z) * inv[2];
        inv[3] = gv.w * rsqrtf(vv.w + 1e-5f); sh[3] = bev.w + (cbv.w - mv.w) * inv[3];
        #pragma unroll
        for (int mt = 0; mt < 2; mt++) {
            us4 pk;
            #pragma unroll
            for (int r = 0; r < 4; r++) {
                float y = acc2[nt][mt][r] * inv[r] + sh[r];
                y = y > 0.f ? y : 0.f;
                pk[r] = f2b(y);
            }
            *(us4*)&Hs[(w * 32 + mt * 16 + lc) * 72 + nt * 16 + quad * 4] = pk;
        }
    }
    // own-wave rows; DS pipe in-order -> read back without barrier
    bf16x8 aH[2][2];
    #pragma unroll
    for (int mt = 0; mt < 2; mt++)
        #pragma unroll
        for (int kc = 0; kc < 2; kc++)
            aH[mt][kc] = *(const bf16x8*)&Hs[(w * 32 + mt * 16 + lc) * 72 + kc * 32 + quad * 8];

    // ---- q, k: C' = W · H^T (wq pre-scaled by 0.125; bias scaled here) ---
    for (int p = 0; p < 2; p++) {
        const unsigned short* wsrc = p ? wkp : wqp;
        const float* bsrc = p ? bk : bq;
        unsigned short* osrc = p ? ko : qo;
        const float bscl = p ? 1.0f : 0.125f;
        #pragma unroll
        for (int nt = 0; nt < 4; nt++) {
            bf16x8 aW[2];
            #pragma unroll
            for (int kc = 0; kc < 2; kc++)
                aW[kc] = *(const bf16x8*)(wsrc + (nt * 16 + lc) * 64 + kc * 32 + quad * 8);
            float4 bb = *(const float4*)&bsrc[nt * 16 + quad * 4];
            bb.x *= bscl; bb.y *= bscl; bb.z *= bscl; bb.w *= bscl;
            #pragma unroll
            for (int mt = 0; mt < 2; mt++) {
                f32x4 a = {0.f, 0.f, 0.f, 0.f};
                a = __builtin_amdgcn_mfma_f32_16x16x32_bf16(aW[0], aH[mt][0], a, 0, 0, 0);
                a = __builtin_amdgcn_mfma_f32_16x16x32_bf16(aW[1], aH[mt][1], a, 0, 0, 0);
                us4 pk;
                pk[0] = f2b(a[0] + bb.x); pk[1] = f2b(a[1] + bb.y);
                pk[2] = f2b(a[2] + bb.z); pk[3] = f2b(a[3] + bb.w);
                *(us4*)&Cs[(w * 32 + mt * 16 + lc) * 72 + nt * 16 + quad * 4] = pk;
            }
        }
        __syncthreads();
        #pragma unroll
        for (int i = 0; i < 4; i++) {          // 128x64 shorts = 1024 uint4
            int idx = i * 256 + t;
            int row = idx >> 3, dcol = (idx & 7) * 8;
            uint4 rd = *(const uint4*)&Cs[row * 72 + dcol];
            *(uint4*)(osrc + (size_t)(rowbase + row) * 64 + dcol) = rd;
        }
        __syncthreads();
    }

    // ---- v: H · Wv^T; regs along keys -> Vs[d][key] ----------------------
    #pragma unroll
    for (int nt = 0; nt < 4; nt++) {
        bf16x8 bW[2];
        #pragma unroll
        for (int kc = 0; kc < 2; kc++)
            bW[kc] = *(const bf16x8*)(wvp + (nt * 16 + lc) * 64 + kc * 32 + quad * 8);
        const float bvv = bvp[nt * 16 + lc];
        #pragma unroll
        for (int mt = 0; mt < 2; mt++) {
            f32x4 a = {0.f, 0.f, 0.f, 0.f};
            a = __builtin_amdgcn_mfma_f32_16x16x32_bf16(aH[mt][0], bW[0], a, 0, 0, 0);
            a = __builtin_amdgcn_mfma_f32_16x16x32_bf16(aH[mt][1], bW[1], a, 0, 0, 0);
            us4 pk;
            pk[0] = f2b(a[0] + bvv); pk[1] = f2b(a[1] + bvv);
            pk[2] = f2b(a[2] + bvv); pk[3] = f2b(a[3] + bvv);
            *(us4*)&Vs[(nt * 16 + lc) * 136 + w * 32 + mt * 16 + quad * 4] = pk;
        }
    }
    __syncthreads();
    #pragma unroll
    for (int i = 0; i < 4; i++) {              // 64x128 shorts = 1024 uint4
        int idx = i * 256 + t;
        int d = idx >> 4, ch = (idx & 15) * 8;
        uint4 rd = *(const uint4*)&Vs[d * 136 + ch];
        *(uint4*)(vt + ((size_t)b * 64 + d) * 512 + l0 + ch) = rd;
    }
}

// ---------------------------------------------------------------------------
// Kernel B: MFMA flash attention + pooling, double-buffered LDS.
// Block = (b, 128-row q-tile), 4 waves x 32 rows. One barrier per 64-key
// stage; loads for s+1 issue before compute(s), vmcnt wait lands after it.
// LDS 38.9 KB -> 4 blocks/CU. No-max softmax (q pre-scaled by 1/8).
// ---------------------------------------------------------------------------
__global__ __launch_bounds__(256) void attn_mfma(
    const unsigned short* __restrict__ q, const unsigned short* __restrict__ k,
    const unsigned short* __restrict__ vt, float* __restrict__ partial)
{
    const int b = blockIdx.x, qt = blockIdx.y, t = threadIdx.x;
    const int w = t >> 6, lane = t & 63, quad = lane >> 4, lc = lane & 15;

    __shared__ unsigned short Kb[2][4096];     // 64 keys x 64 d, frag order
    __shared__ unsigned short Vb[2][4096];     // 64 d x 64 keys, frag order
    __shared__ unsigned short Ps[4][16][40];   // per-wave, one rt at a time
    __shared__ float red[4][64];

    bf16x8 aQ[2][2];
    #pragma unroll
    for (int rt = 0; rt < 2; rt++) {
        const unsigned short* qrow =
            q + (size_t)(b * LL + qt * 128 + w * 32 + rt * 16 + lc) * 64;
        aQ[rt][0] = *(const bf16x8*)(qrow + quad * 8);
        aQ[rt][1] = *(const bf16x8*)(qrow + 32 + quad * 8);
    }

    f32x4 outacc[2][4];
    #pragma unroll
    for (int rt = 0; rt < 2; rt++)
        #pragma unroll
        for (int dt = 0; dt < 4; dt++) outacc[rt][dt] = (f32x4){0.f, 0.f, 0.f, 0.f};
    float den[2][4] = {{0.f, 0.f, 0.f, 0.f}, {0.f, 0.f, 0.f, 0.f}};

    const unsigned short* kbase = k + (size_t)b * LL * 64;
    const unsigned short* vbase = vt + (size_t)b * 64 * 512;

    // staging slots: this wave owns u = w*2, w*2+1.
    // K slot u: cc=u>>2, nt=(u>>1)&1, kc=u&1.  V slot u: cc=u>>2, dt=u&3.
    uint4 kreg[2], vreg[2];
    #pragma unroll
    for (int uu = 0; uu < 2; uu++) {
        int u = w * 2 + uu;
        kreg[uu] = *(const uint4*)(kbase +
            (size_t)((u >> 2) * 32 + ((u >> 1) & 1) * 16 + lc) * 64 + (u & 1) * 32 + quad * 8);
        vreg[uu] = *(const uint4*)(vbase +
            (size_t)((u & 3) * 16 + lc) * 512 + (u >> 2) * 32 + quad * 8);
    }
    #pragma unroll
    for (int uu = 0; uu < 2; uu++) {
        int u = w * 2 + uu;
        *(uint4*)&Kb[0][u * 512 + lane * 8] = kreg[uu];
        *(uint4*)&Vb[0][u * 512 + lane * 8] = vreg[uu];
    }
    __syncthreads();

    for (int s = 0; s < 8; s++) {
        const int cur = s & 1;
        if (s < 7) {                           // issue next-stage loads NOW
            #pragma unroll
            for (int uu = 0; uu < 2; uu++) {
                int u = w * 2 + uu;
                kreg[uu] = *(const uint4*)(kbase +
                    (size_t)((s + 1) * 64 + (u >> 2) * 32 + ((u >> 1) & 1) * 16 + lc) * 64
                    + (u & 1) * 32 + quad * 8);
                vreg[uu] = *(const uint4*)(vbase +
                    (size_t)((u & 3) * 16 + lc) * 512 + (s + 1) * 64 + (u >> 2) * 32 + quad * 8);
            }
        }
        #pragma unroll
        for (int cc = 0; cc < 2; cc++) {       // 32 keys per chunk
            bf16x8 bK[2][2];
            #pragma unroll
            for (int nt = 0; nt < 2; nt++)
                #pragma unroll
                for (int kc = 0; kc < 2; kc++)
                    bK[nt][kc] = *(const bf16x8*)&Kb[cur][(cc * 4 + nt * 2 + kc) * 512 + lane * 8];
            bf16x8 bV[4];
            #pragma unroll
            for (int dt = 0; dt < 4; dt++)
                bV[dt] = *(const bf16x8*)&Vb[cur][(cc * 4 + dt) * 512 + lane * 8];
            #pragma unroll
            for (int rt = 0; rt < 2; rt++) {
                #pragma unroll
                for (int nt = 0; nt < 2; nt++) {
                    f32x4 sv = {0.f, 0.f, 0.f, 0.f};
                    sv = __builtin_amdgcn_mfma_f32_16x16x32_bf16(aQ[rt][0], bK[nt][0], sv, 0, 0, 0);
                    sv = __builtin_amdgcn_mfma_f32_16x16x32_bf16(aQ[rt][1], bK[nt][1], sv, 0, 0, 0);
                    #pragma unroll
                    for (int reg = 0; reg < 4; reg++) {
                        float p = __expf(sv[reg]);    // q pre-scaled by 1/8
                        den[rt][reg] += p;
                        Ps[w][quad * 4 + reg][nt * 16 + lc] = f2b(p);
                    }
                }
                // C->A transform via per-wave LDS (in-order DS pipe)
                bf16x8 aP = *(const bf16x8*)&Ps[w][lc][quad * 8];
                #pragma unroll
                for (int dt = 0; dt < 4; dt++)
                    outacc[rt][dt] = __builtin_amdgcn_mfma_f32_16x16x32_bf16(
                        aP, bV[dt], outacc[rt][dt], 0, 0, 0);
            }
        }
        if (s < 7) {                           // write next buffer, 1 barrier
            #pragma unroll
            for (int uu = 0; uu < 2; uu++) {
                int u = w * 2 + uu;
                *(uint4*)&Kb[cur ^ 1][u * 512 + lane * 8] = kreg[uu];
                *(uint4*)&Vb[cur ^ 1][u * 512 + lane * 8] = vreg[uu];
            }
            __syncthreads();
        }
    }

    // denominators: reduce over the quad's 16 lanes (key mod-16 classes)
    #pragma unroll
    for (int rt = 0; rt < 2; rt++)
        #pragma unroll
        for (int reg = 0; reg < 4; reg++) {
            float d2 = den[rt][reg];
            d2 += __shfl_xor(d2, 1);  d2 += __shfl_xor(d2, 2);
            d2 += __shfl_xor(d2, 4);  d2 += __shfl_xor(d2, 8);
            den[rt][reg] = d2;
        }
    // pooled partials over this wave's 32 rows
    #pragma unroll
    for (int dt = 0; dt < 4; dt++) {
        float ps = 0.f;
        #pragma unroll
        for (int rt = 0; rt < 2; rt++)
            #pragma unroll
            for (int reg = 0; reg < 4; reg++)
                ps += outacc[rt][dt][reg] / den[rt][reg];
        ps += __shfl_xor(ps, 16);
        ps += __shfl_xor(ps, 32);
        if (quad == 0) red[w][dt * 16 + lc] = ps;
    }
    __syncthreads();
    if (t < 64)
        partial[(size_t)(b * 4 + qt) * 64 + t] =
            red[0][t] + red[1][t] + red[2][t] + red[3][t];
}

// ---------------------------------------------------------------------------
// Kernel C: pooled = (sum of 4 partials)/512 ; logits = pooled @ fc_w^T + fc_b
// ---------------------------------------------------------------------------
__global__ __launch_bounds__(64) void fc_kernel(
    const float* __restrict__ partial,
    const float* __restrict__ fcw, const float* __restrict__ fcb,
    float* __restrict__ outp)
{
    const int b = blockIdx.x, t = threadIdx.x;
    __shared__ float pool[64];
    float s = 0.f;
    #pragma unroll
    for (int p = 0; p < 4; p++) s += partial[((size_t)b * 4 + p) * 64 + t];
    pool[t] = s * (1.0f / 512.0f);
    __syncthreads();
    if (t < NCLASS) {
        float acc = fcb[t];
        #pragma unroll
        for (int d = 0; d < 64; d++) acc += pool[d] * fcw[t * 64 + d];
        outp[b * NCLASS + t] = acc;
    }
}

// ---------------------------------------------------------------------------
extern "C" void kernel_launch(void* const* d_in, const int* in_sizes, int n_in,
                              void* d_out, int out_size, void* d_ws, size_t ws_size,
                              hipStream_t stream)
{
    const float* x   = (const float*)d_in[0];
    const float* w1  = (const float*)d_in[1];
    const float* cb1 = (const float*)d_in[2];
    const float* g1  = (const float*)d_in[3];
    const float* be1 = (const float*)d_in[4];
    const float* m1  = (const float*)d_in[5];
    const float* v1  = (const float*)d_in[6];
    const float* w2  = (const float*)d_in[7];
    const float* cb2 = (const float*)d_in[8];
    const float* g2  = (const float*)d_in[9];
    const float* be2 = (const float*)d_in[10];
    const float* m2  = (const float*)d_in[11];
    const float* v2  = (const float*)d_in[12];
    const float* wq  = (const float*)d_in[13];
    const float* bq  = (const float*)d_in[14];
    const float* wk  = (const float*)d_in[15];
    const float* bk  = (const float*)d_in[16];
    const float* wv  = (const float*)d_in[17];
    const float* bv  = (const float*)d_in[18];
    const float* fcw = (const float*)d_in[19];
    const float* fcb = (const float*)d_in[20];
    float* out = (float*)d_out;

    char* ws = (char*)d_ws;
    unsigned short* qo = (unsigned short*)(ws);                 // 16,777,216 B
    unsigned short* ko = (unsigned short*)(ws + 16777216u);
    unsigned short* vt = (unsigned short*)(ws + 33554432u);
    float* partial     = (float*)(ws + 50331648u);              // 262,144 B
    unsigned short* w2p = (unsigned short*)(ws + 50593792u);    // 12,288 B
    unsigned short* wqp = (unsigned short*)(ws + 50606080u);    // 8,192 B
    unsigned short* wkp = (unsigned short*)(ws + 50614272u);    // 8,192 B
    unsigned short* wvp = (unsigned short*)(ws + 50622464u);    // 8,192 B

    prep_weights<<<dim3(1), 256, 0, stream>>>(w2, wq, wk, wv, w2p, wqp, wkp, wvp);
    conv_qkv<<<dim3(NB, 4), 256, 0, stream>>>(x, w1, cb1, g1, be1, m1, v1,
                                              cb2, g2, be2, m2, v2,
                                              bq, bk, bv,
                                              w2p, wqp, wkp, wvp,
                                              qo, ko, vt);
    attn_mfma<<<dim3(NB, 4), 256, 0, stream>>>(qo, ko, vt, partial);
    fc_kernel<<<dim3(NB), 64, 0, stream>>>(partial, fcw, fcb, out);
}

// Round 8
// 172.594 us; speedup vs baseline: 1.3149x; 1.0068x over previous
//
#include <hip/hip_runtime.h>
#include <hip/hip_bf16.h>

// B=256, C_IN=6, L=512, C1=32, C2=D=64, NCLASS=10.
// ws: qo bf16 @0, ko @16M, vt [b][d][key] @32M, partial f32 @48M,
//     prepped bf16 weights @50.59M (w2p k'-packed, wqp(x0.125), wkp, wvp).

#define NB 256
#define LL 512
#define CIN 6
#define C1 32
#define C2 64
#define NCLASS 10

typedef __bf16 bf16x8 __attribute__((ext_vector_type(8)));
typedef float f32x4 __attribute__((ext_vector_type(4)));
typedef unsigned short us4 __attribute__((ext_vector_type(4)));

static __device__ __forceinline__ unsigned short f2b(float f) {
    __bf16 h = (__bf16)f;                       // RNE f32->bf16
    return __builtin_bit_cast(unsigned short, h);
}

// ---------------------------------------------------------------------------
// Kernel P: one-time weight conversion to bf16 (runs every launch; ~2 us).
// w2p[c2][k'=dl*32+ci]; wqp = wq * 0.125 (folds 1/sqrt(64), exact); wkp; wvp.
// ---------------------------------------------------------------------------
__global__ __launch_bounds__(256) void prep_weights(
    const float* __restrict__ w2, const float* __restrict__ wq,
    const float* __restrict__ wk, const float* __restrict__ wv,
    unsigned short* __restrict__ w2p, unsigned short* __restrict__ wqp,
    unsigned short* __restrict__ wkp, unsigned short* __restrict__ wvp)
{
    const int t = threadIdx.x;
    for (int idx = t; idx < 2048; idx += 256) {
        int c2 = idx >> 5, ci = idx & 31;
        const float* wp = w2 + c2 * 96 + ci * 3;
        w2p[c2 * 96 +      ci] = f2b(wp[0]);
        w2p[c2 * 96 + 32 + ci] = f2b(wp[1]);
        w2p[c2 * 96 + 64 + ci] = f2b(wp[2]);
    }
    for (int idx = t; idx < 4096; idx += 256) {
        wqp[idx] = f2b(wq[idx] * 0.125f);
        wkp[idx] = f2b(wk[idx]);
        wvp[idx] = f2b(wv[idx]);
    }
}

// ---------------------------------------------------------------------------
// Kernel A: conv1(VALU) -> conv2(MFMA) -> bn2+relu -> q/k/v MFMA.
// Block = (b, 128 L-rows), grid 1024. Weight frags read directly from global
// bf16 (L2-resident) -> zero per-block weight staging. Peak LDS 18.4 KB.
// ---------------------------------------------------------------------------
__global__ __launch_bounds__(256) void conv_qkv(
    const float* __restrict__ x,
    const float* __restrict__ w1, const float* __restrict__ cb1,
    const float* __restrict__ g1, const float* __restrict__ be1,
    const float* __restrict__ m1, const float* __restrict__ v1,
    const float* __restrict__ cb2,
    const float* __restrict__ g2, const float* __restrict__ be2,
    const float* __restrict__ m2, const float* __restrict__ v2,
    const float* __restrict__ bq, const float* __restrict__ bk,
    const float* __restrict__ bvp,
    const unsigned short* __restrict__ w2p, const unsigned short* __restrict__ wqp,
    const unsigned short* __restrict__ wkp, const unsigned short* __restrict__ wvp,
    unsigned short* __restrict__ qo, unsigned short* __restrict__ ko,
    unsigned short* __restrict__ vt)
{
    const int b  = blockIdx.x;
    const int l0 = blockIdx.y * 128;
    const int t  = threadIdx.x;
    const int w = t >> 6, lane = t & 63, quad = lane >> 4, lc = lane & 15;
    const int rowbase = b * LL + l0;

    // aliased phases:
    //  A: xs[6][132] f32 @0 (3168) | h1b[130][40] @3168 (10400)  = 13568 B
    //  B: Hs[128][72] @0 (18432)   C: Cs[128][72] @0   D: Vs[64][136] @0
    __shared__ __align__(16) char smem[18432];
    float*          xs  = (float*)smem;
    unsigned short* h1b = (unsigned short*)(smem + 3168);
    unsigned short* Hs  = (unsigned short*)smem;
    unsigned short* Cs  = (unsigned short*)smem;
    unsigned short* Vs  = (unsigned short*)smem;

    for (int idx = t; idx < CIN * 132; idx += 256) {
        int c = idx / 132, j = idx % 132;
        int l = l0 - 2 + j;
        xs[c * 132 + j] = (l >= 0 && l < LL) ? x[((size_t)b * CIN + c) * LL + l] : 0.f;
    }
    __syncthreads();

    // ---- conv1 + bn1 + relu -> h1b[j][ci], j=0..129 <-> pos l0-1+j -------
    for (int idx = t; idx < 130 * C1; idx += 256) {
        int j = idx >> 5, c = idx & 31;
        int p = l0 - 1 + j;
        float y = 0.f;
        if (p >= 0 && p < LL) {
            float inv = g1[c] * rsqrtf(v1[c] + 1e-5f);
            float sh  = be1[c] + (cb1[c] - m1[c]) * inv;
            float acc = 0.f;
            #pragma unroll
            for (int ci = 0; ci < CIN; ci++) {
                const float* wp = w1 + (c * CIN + ci) * 3;
                acc += xs[ci * 132 + j] * wp[0] + xs[ci * 132 + j + 1] * wp[1]
                     + xs[ci * 132 + j + 2] * wp[2];
            }
            y = acc * inv + sh;
            y = y > 0.f ? y : 0.f;
        }
        h1b[j * 40 + c] = f2b(y);
    }
    __syncthreads();

    // ---- conv2: C' = W2 · X^T  (M=64 c2, N=128 rows, K=96) ---------------
    bf16x8 bX[2][3], aW2[4][3];
    #pragma unroll
    for (int mt = 0; mt < 2; mt++)
        #pragma unroll
        for (int kc = 0; kc < 3; kc++)
            bX[mt][kc] = *(const bf16x8*)&h1b[(w * 32 + mt * 16 + lc + kc) * 40 + quad * 8];
    #pragma unroll
    for (int nt = 0; nt < 4; nt++)
        #pragma unroll
        for (int kc = 0; kc < 3; kc++)
            aW2[nt][kc] = *(const bf16x8*)(w2p + (nt * 16 + lc) * 96 + kc * 32 + quad * 8);

    f32x4 acc2[4][2];
    #pragma unroll
    for (int nt = 0; nt < 4; nt++)
        #pragma unroll
        for (int mt = 0; mt < 2; mt++) {
            f32x4 a = {0.f, 0.f, 0.f, 0.f};
            a = __builtin_amdgcn_mfma_f32_16x16x32_bf16(aW2[nt][0], bX[mt][0], a, 0, 0, 0);
            a = __builtin_amdgcn_mfma_f32_16x16x32_bf16(aW2[nt][1], bX[mt][1], a, 0, 0, 0);
            acc2[nt][mt] = __builtin_amdgcn_mfma_f32_16x16x32_bf16(aW2[nt][2], bX[mt][2], a, 0, 0, 0);
        }
    __syncthreads();                       // region A dead

    // ---- bn2 + relu -> Hs[row][c2] (wave-private rows) -------------------
    #pragma unroll
    for (int nt = 0; nt < 4; nt++) {
        const float4 gv  = *(const float4*)&g2[nt * 16 + quad * 4];
        const float4 vv  = *(const float4*)&v2[nt * 16 + quad * 4];
        const float4 bev = *(const float4*)&be2[nt * 16 + quad * 4];
        const float4 cbv = *(const float4*)&cb2[nt * 16 + quad * 4];
        const float4 mv  = *(const float4*)&m2[nt * 16 + quad * 4];
        float inv[4], sh[4];
        inv[0] = gv.x * rsqrtf(vv.x + 1e-5f); sh[0] = bev.x + (cbv.x - mv.x) * inv[0];
        inv[1] = gv.y * rsqrtf(vv.y + 1e-5f); sh[1] = bev.y + (cbv.y - mv.y) * inv[1];
        inv[2] = gv.z * rsqrtf(vv.z + 1e-5f); sh[2] = bev.z + (cbv.z - mv.z) * inv[2];
        inv[3] = gv.w * rsqrtf(vv.w + 1e-5f); sh[3] = bev.w + (cbv.w - mv.w) * inv[3];
        #pragma unroll
        for (int mt = 0; mt < 2; mt++) {
            us4 pk;
            #pragma unroll
            for (int r = 0; r < 4; r++) {
                float y = acc2[nt][mt][r] * inv[r] + sh[r];
                y = y > 0.f ? y : 0.f;
                pk[r] = f2b(y);
            }
            *(us4*)&Hs[(w * 32 + mt * 16 + lc) * 72 + nt * 16 + quad * 4] = pk;
        }
    }
    // own-wave rows; DS pipe in-order -> read back without barrier
    bf16x8 aH[2][2];
    #pragma unroll
    for (int mt = 0; mt < 2; mt++)
        #pragma unroll
        for (int kc = 0; kc < 2; kc++)
            aH[mt][kc] = *(const bf16x8*)&Hs[(w * 32 + mt * 16 + lc) * 72 + kc * 32 + quad * 8];

    // ---- q, k: C' = W · H^T (wq pre-scaled by 0.125; bias scaled here) ---
    for (int p = 0; p < 2; p++) {
        const unsigned short* wsrc = p ? wkp : wqp;
        const float* bsrc = p ? bk : bq;
        unsigned short* osrc = p ? ko : qo;
        const float bscl = p ? 1.0f : 0.125f;
        #pragma unroll
        for (int nt = 0; nt < 4; nt++) {
            bf16x8 aW[2];
            #pragma unroll
            for (int kc = 0; kc < 2; kc++)
                aW[kc] = *(const bf16x8*)(wsrc + (nt * 16 + lc) * 64 + kc * 32 + quad * 8);
            float4 bb = *(const float4*)&bsrc[nt * 16 + quad * 4];
            bb.x *= bscl; bb.y *= bscl; bb.z *= bscl; bb.w *= bscl;
            #pragma unroll
            for (int mt = 0; mt < 2; mt++) {
                f32x4 a = {0.f, 0.f, 0.f, 0.f};
                a = __builtin_amdgcn_mfma_f32_16x16x32_bf16(aW[0], aH[mt][0], a, 0, 0, 0);
                a = __builtin_amdgcn_mfma_f32_16x16x32_bf16(aW[1], aH[mt][1], a, 0, 0, 0);
                us4 pk;
                pk[0] = f2b(a[0] + bb.x); pk[1] = f2b(a[1] + bb.y);
                pk[2] = f2b(a[2] + bb.z); pk[3] = f2b(a[3] + bb.w);
                *(us4*)&Cs[(w * 32 + mt * 16 + lc) * 72 + nt * 16 + quad * 4] = pk;
            }
        }
        __syncthreads();
        #pragma unroll
        for (int i = 0; i < 4; i++) {          // 128x64 shorts = 1024 uint4
            int idx = i * 256 + t;
            int row = idx >> 3, dcol = (idx & 7) * 8;
            uint4 rd = *(const uint4*)&Cs[row * 72 + dcol];
            *(uint4*)(osrc + (size_t)(rowbase + row) * 64 + dcol) = rd;
        }
        __syncthreads();
    }

    // ---- v: H · Wv^T; regs along keys -> Vs[d][key] ----------------------
    #pragma unroll
    for (int nt = 0; nt < 4; nt++) {
        bf16x8 bW[2];
        #pragma unroll
        for (int kc = 0; kc < 2; kc++)
            bW[kc] = *(const bf16x8*)(wvp + (nt * 16 + lc) * 64 + kc * 32 + quad * 8);
        const float bvv = bvp[nt * 16 + lc];
        #pragma unroll
        for (int mt = 0; mt < 2; mt++) {
            f32x4 a = {0.f, 0.f, 0.f, 0.f};
            a = __builtin_amdgcn_mfma_f32_16x16x32_bf16(aH[mt][0], bW[0], a, 0, 0, 0);
            a = __builtin_amdgcn_mfma_f32_16x16x32_bf16(aH[mt][1], bW[1], a, 0, 0, 0);
            us4 pk;
            pk[0] = f2b(a[0] + bvv); pk[1] = f2b(a[1] + bvv);
            pk[2] = f2b(a[2] + bvv); pk[3] = f2b(a[3] + bvv);
            *(us4*)&Vs[(nt * 16 + lc) * 136 + w * 32 + mt * 16 + quad * 4] = pk;
        }
    }
    __syncthreads();
    #pragma unroll
    for (int i = 0; i < 4; i++) {              // 64x128 shorts = 1024 uint4
        int idx = i * 256 + t;
        int d = idx >> 4, ch = (idx & 15) * 8;
        uint4 rd = *(const uint4*)&Vs[d * 136 + ch];
        *(uint4*)(vt + ((size_t)b * 64 + d) * 512 + l0 + ch) = rd;
    }
}

// ---------------------------------------------------------------------------
// Kernel B: MFMA flash attention + pooling, double-buffered LDS.
// Block = (b, 256-row q-tile), 4 waves x 64 rows (rt=4 independent chains).
// K/V staged once per 64-key stage for 256 q-rows (2x less k/v traffic than
// 128-row tiles). Private Ps slab per (wave,rt) kills the WAR serialization
// on the in-order DS pipe. LDS 53 KB -> 2 blocks/CU (grid 512 = 2/CU).
// ---------------------------------------------------------------------------
__global__ __launch_bounds__(256) void attn_mfma(
    const unsigned short* __restrict__ q, const unsigned short* __restrict__ k,
    const unsigned short* __restrict__ vt, float* __restrict__ partial)
{
    const int b = blockIdx.x, qt = blockIdx.y, t = threadIdx.x;
    const int w = t >> 6, lane = t & 63, quad = lane >> 4, lc = lane & 15;

    __shared__ unsigned short Kb[2][4096];     // 64 keys x 64 d, frag order
    __shared__ unsigned short Vb[2][4096];     // 64 d x 64 keys, frag order
    __shared__ unsigned short Ps[4][4][16][40]; // per (wave, rt) slab
    __shared__ float red[4][64];

    bf16x8 aQ[4][2];
    #pragma unroll
    for (int rt = 0; rt < 4; rt++) {
        const unsigned short* qrow =
            q + (size_t)(b * LL + qt * 256 + w * 64 + rt * 16 + lc) * 64;
        aQ[rt][0] = *(const bf16x8*)(qrow + quad * 8);
        aQ[rt][1] = *(const bf16x8*)(qrow + 32 + quad * 8);
    }

    f32x4 outacc[4][4];
    #pragma unroll
    for (int rt = 0; rt < 4; rt++)
        #pragma unroll
        for (int dt = 0; dt < 4; dt++) outacc[rt][dt] = (f32x4){0.f, 0.f, 0.f, 0.f};
    float den[4][4];
    #pragma unroll
    for (int rt = 0; rt < 4; rt++)
        #pragma unroll
        for (int reg = 0; reg < 4; reg++) den[rt][reg] = 0.f;

    const unsigned short* kbase = k + (size_t)b * LL * 64;
    const unsigned short* vbase = vt + (size_t)b * 64 * 512;

    // staging slots: this wave owns u = w*2, w*2+1.
    // K slot u: cc=u>>2, nt=(u>>1)&1, kc=u&1.  V slot u: cc=u>>2, dt=u&3.
    uint4 kreg[2], vreg[2];
    #pragma unroll
    for (int uu = 0; uu < 2; uu++) {
        int u = w * 2 + uu;
        kreg[uu] = *(const uint4*)(kbase +
            (size_t)((u >> 2) * 32 + ((u >> 1) & 1) * 16 + lc) * 64 + (u & 1) * 32 + quad * 8);
        vreg[uu] = *(const uint4*)(vbase +
            (size_t)((u & 3) * 16 + lc) * 512 + (u >> 2) * 32 + quad * 8);
    }
    #pragma unroll
    for (int uu = 0; uu < 2; uu++) {
        int u = w * 2 + uu;
        *(uint4*)&Kb[0][u * 512 + lane * 8] = kreg[uu];
        *(uint4*)&Vb[0][u * 512 + lane * 8] = vreg[uu];
    }
    __syncthreads();

    for (int s = 0; s < 8; s++) {
        const int cur = s & 1;
        if (s < 7) {                           // issue next-stage loads NOW
            #pragma unroll
            for (int uu = 0; uu < 2; uu++) {
                int u = w * 2 + uu;
                kreg[uu] = *(const uint4*)(kbase +
                    (size_t)((s + 1) * 64 + (u >> 2) * 32 + ((u >> 1) & 1) * 16 + lc) * 64
                    + (u & 1) * 32 + quad * 8);
                vreg[uu] = *(const uint4*)(vbase +
                    (size_t)((u & 3) * 16 + lc) * 512 + (s + 1) * 64 + (u >> 2) * 32 + quad * 8);
            }
        }
        #pragma unroll
        for (int cc = 0; cc < 2; cc++) {       // 32 keys per chunk
            bf16x8 bK[2][2];
            #pragma unroll
            for (int nt = 0; nt < 2; nt++)
                #pragma unroll
                for (int kc = 0; kc < 2; kc++)
                    bK[nt][kc] = *(const bf16x8*)&Kb[cur][(cc * 4 + nt * 2 + kc) * 512 + lane * 8];
            bf16x8 bV[4];
            #pragma unroll
            for (int dt = 0; dt < 4; dt++)
                bV[dt] = *(const bf16x8*)&Vb[cur][(cc * 4 + dt) * 512 + lane * 8];
            // 4 independent QK -> exp -> Ps -> PV chains (private Ps slabs)
            #pragma unroll
            for (int rt = 0; rt < 4; rt++) {
                #pragma unroll
                for (int nt = 0; nt < 2; nt++) {
                    f32x4 sv = {0.f, 0.f, 0.f, 0.f};
                    sv = __builtin_amdgcn_mfma_f32_16x16x32_bf16(aQ[rt][0], bK[nt][0], sv, 0, 0, 0);
                    sv = __builtin_amdgcn_mfma_f32_16x16x32_bf16(aQ[rt][1], bK[nt][1], sv, 0, 0, 0);
                    #pragma unroll
                    for (int reg = 0; reg < 4; reg++) {
                        float p = __expf(sv[reg]);    // q pre-scaled by 1/8
                        den[rt][reg] += p;
                        Ps[w][rt][quad * 4 + reg][nt * 16 + lc] = f2b(p);
                    }
                }
                bf16x8 aP = *(const bf16x8*)&Ps[w][rt][lc][quad * 8];
                #pragma unroll
                for (int dt = 0; dt < 4; dt++)
                    outacc[rt][dt] = __builtin_amdgcn_mfma_f32_16x16x32_bf16(
                        aP, bV[dt], outacc[rt][dt], 0, 0, 0);
            }
        }
        if (s < 7) {                           // write next buffer, 1 barrier
            #pragma unroll
            for (int uu = 0; uu < 2; uu++) {
                int u = w * 2 + uu;
                *(uint4*)&Kb[cur ^ 1][u * 512 + lane * 8] = kreg[uu];
                *(uint4*)&Vb[cur ^ 1][u * 512 + lane * 8] = vreg[uu];
            }
            __syncthreads();
        }
    }

    // denominators: reduce over the quad's 16 lanes (key mod-16 classes)
    #pragma unroll
    for (int rt = 0; rt < 4; rt++)
        #pragma unroll
        for (int reg = 0; reg < 4; reg++) {
            float d2 = den[rt][reg];
            d2 += __shfl_xor(d2, 1);  d2 += __shfl_xor(d2, 2);
            d2 += __shfl_xor(d2, 4);  d2 += __shfl_xor(d2, 8);
            den[rt][reg] = d2;
        }
    // pooled partials over this wave's 64 rows
    #pragma unroll
    for (int dt = 0; dt < 4; dt++) {
        float ps = 0.f;
        #pragma unroll
        for (int rt = 0; rt < 4; rt++)
            #pragma unroll
            for (int reg = 0; reg < 4; reg++)
                ps += outacc[rt][dt][reg] / den[rt][reg];
        ps += __shfl_xor(ps, 16);
        ps += __shfl_xor(ps, 32);
        if (quad == 0) red[w][dt * 16 + lc] = ps;
    }
    __syncthreads();
    if (t < 64)
        partial[(size_t)(b * 2 + qt) * 64 + t] =
            red[0][t] + red[1][t] + red[2][t] + red[3][t];
}

// ---------------------------------------------------------------------------
// Kernel C: pooled = (sum of 2 partials)/512 ; logits = pooled @ fc_w^T + fc_b
// ---------------------------------------------------------------------------
__global__ __launch_bounds__(64) void fc_kernel(
    const float* __restrict__ partial,
    const float* __restrict__ fcw, const float* __restrict__ fcb,
    float* __restrict__ outp)
{
    const int b = blockIdx.x, t = threadIdx.x;
    __shared__ float pool[64];
    float s = 0.f;
    #pragma unroll
    for (int p = 0; p < 2; p++) s += partial[((size_t)b * 2 + p) * 64 + t];
    pool[t] = s * (1.0f / 512.0f);
    __syncthreads();
    if (t < NCLASS) {
        float acc = fcb[t];
        #pragma unroll
        for (int d = 0; d < 64; d++) acc += pool[d] * fcw[t * 64 + d];
        outp[b * NCLASS + t] = acc;
    }
}

// ---------------------------------------------------------------------------
extern "C" void kernel_launch(void* const* d_in, const int* in_sizes, int n_in,
                              void* d_out, int out_size, void* d_ws, size_t ws_size,
                              hipStream_t stream)
{
    const float* x   = (const float*)d_in[0];
    const float* w1  = (const float*)d_in[1];
    const float* cb1 = (const float*)d_in[2];
    const float* g1  = (const float*)d_in[3];
    const float* be1 = (const float*)d_in[4];
    const float* m1  = (const float*)d_in[5];
    const float* v1  = (const float*)d_in[6];
    const float* w2  = (const float*)d_in[7];
    const float* cb2 = (const float*)d_in[8];
    const float* g2  = (const float*)d_in[9];
    const float* be2 = (const float*)d_in[10];
    const float* m2  = (const float*)d_in[11];
    const float* v2  = (const float*)d_in[12];
    const float* wq  = (const float*)d_in[13];
    const float* bq  = (const float*)d_in[14];
    const float* wk  = (const float*)d_in[15];
    const float* bk  = (const float*)d_in[16];
    const float* wv  = (const float*)d_in[17];
    const float* bv  = (const float*)d_in[18];
    const float* fcw = (const float*)d_in[19];
    const float* fcb = (const float*)d_in[20];
    float* out = (float*)d_out;

    char* ws = (char*)d_ws;
    unsigned short* qo = (unsigned short*)(ws);                 // 16,777,216 B
    unsigned short* ko = (unsigned short*)(ws + 16777216u);
    unsigned short* vt = (unsigned short*)(ws + 33554432u);
    float* partial     = (float*)(ws + 50331648u);              // 131,072 B
    unsigned short* w2p = (unsigned short*)(ws + 50593792u);    // 12,288 B
    unsigned short* wqp = (unsigned short*)(ws + 50606080u);    // 8,192 B
    unsigned short* wkp = (unsigned short*)(ws + 50614272u);    // 8,192 B
    unsigned short* wvp = (unsigned short*)(ws + 50622464u);    // 8,192 B

    prep_weights<<<dim3(1), 256, 0, stream>>>(w2, wq, wk, wv, w2p, wqp, wkp, wvp);
    conv_qkv<<<dim3(NB, 4), 256, 0, stream>>>(x, w1, cb1, g1, be1, m1, v1,
                                              cb2, g2, be2, m2, v2,
                                              bq, bk, bv,
                                              w2p, wqp, wkp, wvp,
                                              qo, ko, vt);
    attn_mfma<<<dim3(NB, 2), 256, 0, stream>>>(qo, ko, vt, partial);
    fc_kernel<<<dim3(NB), 64, 0, stream>>>(partial, fcw, fcb, out);
}